// Round 19
// baseline (197.387 us; speedup 1.0000x reference)
//
#include <hip/hip_runtime.h>
#include <hip/hip_bf16.h>
#include <math.h>

#define BB 128
#define PP 8732
#define NN 16
#define CC 81
#define IMG 300.0f
#define TILE_ROWS 64
#define NT ((BB * PP) / TILE_ROWS)   // 17464 tiles, exact
#define K1_THREADS 512
#define HALF_P (PP / 2)              // 4366 priors per half-block
#define NW1 (K1_THREADS / 64)        // 8 waves

// ---------------------------------------------------------------------------
// Kernel 1 (v6): 2 blocks per image (grid 256 -> every CU busy), 512 threads,
// SAME per-thread register profile as the proven v4b (no launch-shape
// register squeeze -- r17/r18 lesson). Each block: phase A on its half of
// the priors; publish per-object (v,p) best; ticket-sync with sibling block
// (k3-finalize pattern); combine argmax; scatter overrides in own range;
// phase D on own half -> per-half partials.
// grid = 2*BB blocks, 512 threads
// ---------------------------------------------------------------------------
__global__ __launch_bounds__(K1_THREADS) void k1_match(
    const float* __restrict__ pred_boxes,   // [B,P,4]
    const float* __restrict__ tgt_boxes,    // [B,N,4] pixel cxcywh
    const int*   __restrict__ tgt_labels,   // [B,N]
    const float* __restrict__ dboxes,       // [P,4] cxcywh (clipped)
    int*   __restrict__ tlab_out,           // [B,P]
    float* __restrict__ bbox_half,          // [2*BB]
    int*   __restrict__ pos_half,           // [2*BB]
    float* __restrict__ gv,                 // [2*BB*NN] per-half best iou
    int*   __restrict__ gp,                 // [2*BB*NN] per-half best prior
    int*   __restrict__ img_cnt)            // [BB] zeroed by memset each call
{
    const int b    = blockIdx.x >> 1;
    const int half = blockIdx.x & 1;
    const int base = half * HALF_P;
    const int tid  = threadIdx.x;

    __shared__ float t_cx[NN], t_cy[NN], t_w[NN], t_h[NN];
    __shared__ float t_x0s[NN], t_y0s[NN], t_x1s[NN], t_y1s[NN], t_areas[NN];
    __shared__ int   t_lab[NN];
    __shared__ unsigned char obj_s[HALF_P];
    __shared__ unsigned char chk_s[HALF_P];
    __shared__ float red_v[NN][NW1];
    __shared__ int   red_i[NN][NW1];
    __shared__ int   box_idx_s[NN];
    __shared__ float red_f[NW1];
    __shared__ int   red_c[NW1];

    if (tid < NN) {
        const float* tb = tgt_boxes + ((size_t)b * NN + tid) * 4;
        float cx = tb[0] / IMG, cy = tb[1] / IMG, w = tb[2] / IMG, h = tb[3] / IMG;
        t_cx[tid] = cx; t_cy[tid] = cy; t_w[tid] = w; t_h[tid] = h;
        float x0 = cx - w * 0.5f, y0 = cy - h * 0.5f;
        float x1 = cx + w * 0.5f, y1 = cy + h * 0.5f;
        t_x0s[tid] = x0; t_y0s[tid] = y0; t_x1s[tid] = x1; t_y1s[tid] = y1;
        t_areas[tid] = (x1 - x0) * (y1 - y0);
        t_lab[tid] = tgt_labels[(size_t)b * NN + tid];
    }
    __syncthreads();

    float tx0[NN], ty0[NN], tx1[NN], ty1[NN], tar[NN];
#pragma unroll
    for (int n = 0; n < NN; ++n) {
        tx0[n] = t_x0s[n]; ty0[n] = t_y0s[n];
        tx1[n] = t_x1s[n]; ty1[n] = t_y1s[n];
        tar[n] = t_areas[n];
    }

    float bestv[NN];
    int   bestp[NN];
#pragma unroll
    for (int n = 0; n < NN; ++n) { bestv[n] = -1.0f; bestp[n] = 0x7fffffff; }

    // Phase A on this half's priors
    for (int i = tid; i < HALF_P; i += K1_THREADS) {
        const int p = base + i;
        float4 d = *reinterpret_cast<const float4*>(dboxes + (size_t)p * 4);
        float dx0 = d.x - d.z * 0.5f, dy0 = d.y - d.w * 0.5f;
        float dx1 = d.x + d.z * 0.5f, dy1 = d.y + d.w * 0.5f;
        float dar = (dx1 - dx0) * (dy1 - dy0);

        float iou[NN];
#pragma unroll
        for (int n = 0; n < NN; ++n) {
            float lx = fmaxf(tx0[n], dx0);
            float ly = fmaxf(ty0[n], dy0);
            float rx = fminf(tx1[n], dx1);
            float ry = fminf(ty1[n], dy1);
            float iw = fmaxf(rx - lx, 0.0f);
            float ih = fmaxf(ry - ly, 0.0f);
            float inter = iw * ih;
            float den   = tar[n] + dar - inter;          // > 0 always
            iou[n] = inter * __builtin_amdgcn_rcpf(den); // independent rcp per n
        }
        float bov = iou[0];
#pragma unroll
        for (int n = 1; n < NN; ++n) bov = fmaxf(bov, iou[n]);
        int bidx = 0;
#pragma unroll
        for (int n = NN - 1; n >= 0; --n) if (iou[n] == bov) bidx = n;
#pragma unroll
        for (int n = 0; n < NN; ++n) {
            if (iou[n] > bestv[n]) { bestv[n] = iou[n]; bestp[n] = p; }
        }
        obj_s[i] = (unsigned char)bidx;
        chk_s[i] = (bov > 0.5f) ? 1 : 0;
    }

    // Phase B: block-wide argmax per object (tie -> smaller p)
#pragma unroll
    for (int n = 0; n < NN; ++n) {
        float v = bestv[n]; int ip = bestp[n];
        for (int off = 32; off; off >>= 1) {
            float v2 = __shfl_xor(v, off);
            int   p2 = __shfl_xor(ip, off);
            if (v2 > v || (v2 == v && p2 < ip)) { v = v2; ip = p2; }
        }
        if ((tid & 63) == 0) { red_v[n][tid >> 6] = v; red_i[n][tid >> 6] = ip; }
    }
    __syncthreads();
    if (tid < NN) {
        float v = red_v[tid][0]; int ip = red_i[tid][0];
        for (int w = 1; w < NW1; ++w) {
            float v2 = red_v[tid][w]; int p2 = red_i[tid][w];
            if (v2 > v || (v2 == v && p2 < ip)) { v = v2; ip = p2; }
        }
        gv[blockIdx.x * NN + tid] = v;      // publish per-half best
        gp[blockIdx.x * NN + tid] = ip;
    }
    __threadfence();                        // release published bests
    __syncthreads();
    if (tid == 0) {
        __hip_atomic_fetch_add(&img_cnt[b], 1, __ATOMIC_RELEASE,
                               __HIP_MEMORY_SCOPE_AGENT);
        while (__hip_atomic_load(&img_cnt[b], __ATOMIC_ACQUIRE,
                                 __HIP_MEMORY_SCOPE_AGENT) < 2)
            __builtin_amdgcn_s_sleep(1);
    }
    __syncthreads();                        // sibling's bests now visible
    __threadfence();                        // acquire-order subsequent reads

    // Combine halves (deterministic; equal v -> half 0 = smaller p range)
    if (tid < NN) {
        float v0 = gv[(b * 2 + 0) * NN + tid];
        int   p0 = gp[(b * 2 + 0) * NN + tid];
        float v1 = gv[(b * 2 + 1) * NN + tid];
        int   p1 = gp[(b * 2 + 1) * NN + tid];
        box_idx_s[tid] = (v1 > v0 || (v1 == v0 && p1 < p0)) ? p1 : p0;
    }
    __syncthreads();
    // Phase C: scatter overrides within my range (n ascending = last-wins)
    if (tid == 0) {
        for (int n = 0; n < NN; ++n) {
            int bp = box_idx_s[n];
            if (bp >= base && bp < base + HALF_P)
                obj_s[bp - base] = (unsigned char)n;
        }
    }
    __syncthreads();

    // Phase D: labels, encode, smoothL1 over my half
    float bacc = 0.0f;
    int   pcnt = 0;
    for (int i = tid; i < HALF_P; i += K1_THREADS) {
        const int p = base + i;
        int lab = 0;
        if (chk_s[i]) {
            int n = obj_s[i];
            lab = t_lab[n];
            if (lab != 0) {
                ++pcnt;
                float4 d = *reinterpret_cast<const float4*>(dboxes + (size_t)p * 4);
                float gx = (t_cx[n] - d.x) / (d.z / 10.0f);
                float gy = (t_cy[n] - d.y) / (d.w / 10.0f);
                float gw = logf(t_w[n] / d.z) * 5.0f;
                float gh = logf(t_h[n] / d.w) * 5.0f;
                float4 pv = *reinterpret_cast<const float4*>(pred_boxes + ((size_t)b * PP + p) * 4);
                float dfs[4] = { pv.x - gx, pv.y - gy, pv.z - gw, pv.w - gh };
#pragma unroll
                for (int j = 0; j < 4; ++j) {
                    float ad = fabsf(dfs[j]);
                    bacc += (ad < 1.0f) ? 0.5f * ad * ad : ad - 0.5f;
                }
            }
        }
        tlab_out[(size_t)b * PP + p] = lab;
    }
    for (int off = 32; off; off >>= 1) {
        bacc += __shfl_xor(bacc, off);
        pcnt += __shfl_xor(pcnt, off);
    }
    if ((tid & 63) == 0) { red_f[tid >> 6] = bacc; red_c[tid >> 6] = pcnt; }
    __syncthreads();
    if (tid == 0) {
        float s = 0.0f; int c = 0;
        for (int w = 0; w < NW1; ++w) { s += red_f[w]; c += red_c[w]; }
        bbox_half[blockIdx.x] = s;
        pos_half[blockIdx.x]  = c;
    }
}

// ---------------------------------------------------------------------------
// Kernel 2 (v4): one 64-row tile per 256-thread block, 4 threads per row.
// (byte-identical to rounds 10-16)
// grid = NT x 256
// ---------------------------------------------------------------------------
__global__ __launch_bounds__(256) void k2_cls(
    const float* __restrict__ scores,  // [B*P, C]
    const int*   __restrict__ tlab,    // [B*P]
    float* __restrict__ neg,           // [B*P]
    float* __restrict__ clspos_partial)// [NT]
{
    __shared__ float slds[TILE_ROWS * CC];   // 64 x 81 floats = 20736 B
    const int tid = threadIdx.x;
    const int t   = blockIdx.x;

    const float* g = scores + (size_t)t * (TILE_ROWS * CC);
    for (int i = tid; i < TILE_ROWS * CC; i += 256)
        slds[i] = g[i];                      // coalesced, 256B/wave-instr
    __syncthreads();

    const int row = tid >> 2;                // 0..63
    const int q   = tid & 3;                 // quarter of the row
    const float* myrow = &slds[row * CC];
    const int base = q * 20;

    float x[21];
#pragma unroll
    for (int i = 0; i < 20; ++i) x[i] = myrow[base + i];
    x[20] = (q == 3) ? myrow[80] : -1e30f;

    float m = x[0];
#pragma unroll
    for (int i = 1; i < 21; ++i) m = fmaxf(m, x[i]);
    m = fmaxf(m, __shfl_xor(m, 1));
    m = fmaxf(m, __shfl_xor(m, 2));          // all 4 lanes hold row max M

    float s0 = 0.0f, s1 = 0.0f, s2 = 0.0f, s3 = 0.0f;
#pragma unroll
    for (int i = 0; i < 20; i += 4) {
        s0 += __expf(x[i + 0] - m);
        s1 += __expf(x[i + 1] - m);
        s2 += __expf(x[i + 2] - m);
        s3 += __expf(x[i + 3] - m);
    }
    s0 += __expf(x[20] - m);
    float s = (s0 + s1) + (s2 + s3);
    s += __shfl_xor(s, 1);
    s += __shfl_xor(s, 2);                   // all 4 lanes hold row sum S

    float acc = 0.0f;
    if (q == 0) {
        long long r = (long long)t * TILE_ROWS + row;
        int   lab = tlab[r];
        float cls = m + __logf(s) - slds[row * CC + lab];
        if (lab != 0) { acc = cls; neg[r] = 0.0f; }
        else          { neg[r] = cls; }
    }

    for (int off = 32; off; off >>= 1) acc += __shfl_xor(acc, off);
    __shared__ float wsum[4];
    if ((tid & 63) == 0) wsum[tid >> 6] = acc;
    __syncthreads();
    if (tid == 0)
        clspos_partial[t] = wsum[0] + wsum[1] + wsum[2] + wsum[3];
}

// ---------------------------------------------------------------------------
// Kernel 3 (v7b): as rounds 14-16, but pos/bbox come as per-half arrays
// (k = (pos_half[2b]+pos_half[2b+1])*3; finalize sums 256 halves).
// grid = BB x 256
// ---------------------------------------------------------------------------
#define HREP 32
#define HPAD 257
#define CH   ((NT + BB - 1) / BB)   // 137 slice elements per block
__global__ __launch_bounds__(256) void k3_topk_final(
    const float* __restrict__ neg,
    const int*   __restrict__ pos_half,     // [2*BB]
    const float* __restrict__ clspos_partial,
    const float* __restrict__ bbox_half,    // [2*BB]
    float* __restrict__ hard_partial,
    float* __restrict__ clspos_red,
    int*   __restrict__ done,
    float* __restrict__ out)
{
    const int b    = blockIdx.x;
    const int tid  = threadIdx.x;
    const int lane = tid & 63;
    const int wv   = tid >> 6;                // 0..3
    const int rep  = lane >> 1;               // 32 replicas, 2 lanes each

    __shared__ unsigned int vals[PP];         // 34928 B
    __shared__ int histR[HREP * HPAD];        // 32896 B
    __shared__ int waveTot[4];
    __shared__ unsigned int s_prefix;
    __shared__ int s_kk;
    __shared__ float wsum[4];
    __shared__ float wsumc[4];
    __shared__ int s_last;

    for (int i = tid; i < PP; i += 256)
        vals[i] = __float_as_uint(neg[(size_t)b * PP + i]);

    {
        int start = b * CH;
        int end   = start + CH; if (end > NT) end = NT;
        float cv = (start + tid < end) ? clspos_partial[start + tid] : 0.0f;
        for (int off = 32; off; off >>= 1) cv += __shfl_xor(cv, off);
        if (lane == 0) wsumc[wv] = cv;
    }

    int k = (pos_half[2 * b] + pos_half[2 * b + 1]) * 3;
    if (k > PP) k = PP;
    if (tid == 0) { s_prefix = 0u; s_kk = k; }
    __syncthreads();
    if (tid == 0)
        clspos_red[b] = wsumc[0] + wsumc[1] + wsumc[2] + wsumc[3];

    float hp = 0.0f;
    if (k > 0) {
        unsigned int prefmask = 0u;
        for (int round = 0; round < 4; ++round) {
            const int shift = 24 - 8 * round;
            for (int i = tid; i < HREP * HPAD; i += 256) histR[i] = 0;
            __syncthreads();
            const unsigned int pref = s_prefix;
            const int kkR = s_kk;
            for (int i = tid; i < PP; i += 256) {
                unsigned int v = vals[i];
                if ((v & prefmask) == pref)
                    atomicAdd(&histR[rep * HPAD + ((v >> shift) & 0xFF)], 1);
            }
            __syncthreads();
            int myh = 0;
#pragma unroll 8
            for (int r = 0; r < HREP; ++r) myh += histR[r * HPAD + tid];
            int s = myh;
#pragma unroll
            for (int off = 1; off < 64; off <<= 1) {
                int v = __shfl_down(s, off);
                if (lane + off < 64) s += v;
            }
            if (lane == 0) waveTot[wv] = s;
            __syncthreads();
            int addhi = 0;
            for (int w2 = wv + 1; w2 < 4; ++w2) addhi += waveTot[w2];
            s += addhi;
            int sg = s - myh;
            if (sg < kkR && sg + myh >= kkR) {
                s_prefix = pref | ((unsigned int)tid << shift);
                s_kk     = kkR - sg;
            }
            prefmask |= (0xFFu << shift);
        }
        __syncthreads();

        unsigned int t = s_prefix;
        int kk = s_kk;
        float tf = __uint_as_float(t);

        float acc = 0.0f;
        for (int i = tid; i < PP; i += 256) {
            unsigned int v = vals[i];
            if (v > t) acc += __uint_as_float(v);
        }
        for (int off = 32; off; off >>= 1) acc += __shfl_xor(acc, off);
        if (lane == 0) wsum[wv] = acc;
        __syncthreads();
        if (tid == 0)
            hp = wsum[0] + wsum[1] + wsum[2] + wsum[3] + (float)kk * tf;
    }
    if (tid == 0) hard_partial[b] = hp;

    __threadfence();
    if (tid == 0) s_last = (atomicAdd(done, 1) == BB - 1) ? 1 : 0;
    __syncthreads();
    if (!s_last) return;
    __threadfence();

    float cacc = 0.0f, bacc = 0.0f, hacc = 0.0f, pacc = 0.0f;
    if (tid < BB) {
        cacc = clspos_red[tid];
        hacc = hard_partial[tid];
    }
    bacc = bbox_half[tid];                  // 256 halves, all threads
    pacc = (float)pos_half[tid];
    __shared__ float sc[256], sb[256], sh[256], sp[256];
    sc[tid] = cacc; sb[tid] = bacc; sh[tid] = hacc; sp[tid] = pacc;
    __syncthreads();
    for (int off = 128; off; off >>= 1) {
        if (tid < off) {
            sc[tid] += sc[tid + off];
            sb[tid] += sb[tid + off];
            sh[tid] += sh[tid + off];
            sp[tid] += sp[tid + off];
        }
        __syncthreads();
    }
    if (tid == 0) {
        float npos = fmaxf(sp[0], 1.0f);
        out[0] = (sc[0] + sh[0]) / npos + sb[0] / (npos * 4.0f);
    }
}

// ---------------------------------------------------------------------------
extern "C" void kernel_launch(void* const* d_in, const int* in_sizes, int n_in,
                              void* d_out, int out_size, void* d_ws, size_t ws_size,
                              hipStream_t stream) {
    const float* pred_boxes  = (const float*)d_in[0];
    const float* pred_scores = (const float*)d_in[1];
    const float* tgt_boxes   = (const float*)d_in[2];
    const int*   tgt_labels  = (const int*)d_in[3];
    const float* dboxes      = (const float*)d_in[4];
    float* out = (float*)d_out;

    char* ws = (char*)d_ws;
    int*   tlab           = (int*)ws;   ws += (size_t)BB * PP * sizeof(int);
    float* neg            = (float*)ws; ws += (size_t)BB * PP * sizeof(float);
    int*   k3_done        = (int*)ws;   ws += 4 * sizeof(int);
    int*   img_cnt        = (int*)ws;   ws += BB * sizeof(int);
    int*   pos_half       = (int*)ws;   ws += 2 * BB * sizeof(int);
    float* bbox_half      = (float*)ws; ws += 2 * BB * sizeof(float);
    float* hard_partial   = (float*)ws; ws += BB * sizeof(float);
    float* clspos_red     = (float*)ws; ws += BB * sizeof(float);
    float* gv             = (float*)ws; ws += 2 * BB * NN * sizeof(float);
    int*   gp             = (int*)ws;   ws += 2 * BB * NN * sizeof(int);
    float* clspos_partial = (float*)ws; ws += (size_t)NT * sizeof(float);

    // zero sync counters (k3_done + img_cnt contiguous); graph-capturable
    hipMemsetAsync(k3_done, 0, (4 + BB) * sizeof(int), stream);

    k1_match<<<2 * BB, K1_THREADS, 0, stream>>>(pred_boxes, tgt_boxes, tgt_labels,
                                                dboxes, tlab, bbox_half, pos_half,
                                                gv, gp, img_cnt);
    k2_cls<<<NT, 256, 0, stream>>>(pred_scores, tlab, neg, clspos_partial);
    k3_topk_final<<<BB, 256, 0, stream>>>(neg, pos_half, clspos_partial,
                                          bbox_half, hard_partial, clspos_red,
                                          k3_done, out);
}

// Round 20
// 145.692 us; speedup vs baseline: 1.3548x; 1.3548x over previous
//
#include <hip/hip_runtime.h>
#include <hip/hip_bf16.h>
#include <math.h>

#define BB 128
#define PP 8732
#define NN 16
#define CC 81
#define IMG 300.0f
#define TILE_ROWS 64
#define NT ((BB * PP) / TILE_ROWS)   // 17464 tiles, exact
#define K1_THREADS 512

// ---------------------------------------------------------------------------
// Kernel 1 (v4b): ILP-restructured matching. (byte-identical to round 16's
// 140.1us best config)
// grid = BB blocks, 512 threads
// ---------------------------------------------------------------------------
__global__ __launch_bounds__(K1_THREADS) void k1_match(
    const float* __restrict__ pred_boxes,   // [B,P,4]
    const float* __restrict__ tgt_boxes,    // [B,N,4] pixel cxcywh
    const int*   __restrict__ tgt_labels,   // [B,N]
    const float* __restrict__ dboxes,       // [P,4] cxcywh (clipped)
    int*   __restrict__ tlab_out,           // [B,P]
    float* __restrict__ bbox_partial,       // [B]
    int*   __restrict__ pos_count,          // [B]
    int*   __restrict__ k3_done)            // [1] completion counter
{
    const int b   = blockIdx.x;
    const int tid = threadIdx.x;
    const int NW  = K1_THREADS / 64;

    if (b == 0 && tid == 0) *k3_done = 0;   // replay-safe reset (runs before k3)

    __shared__ float t_cx[NN], t_cy[NN], t_w[NN], t_h[NN];
    __shared__ float t_x0s[NN], t_y0s[NN], t_x1s[NN], t_y1s[NN], t_areas[NN];
    __shared__ int   t_lab[NN];
    __shared__ unsigned char obj_s[PP];
    __shared__ unsigned char chk_s[PP];
    __shared__ float red_v[NN][NW];
    __shared__ int   red_i[NN][NW];
    __shared__ int   box_idx_s[NN];
    __shared__ float red_f[NW];
    __shared__ int   red_c[NW];

    if (tid < NN) {
        const float* tb = tgt_boxes + ((size_t)b * NN + tid) * 4;
        float cx = tb[0] / IMG, cy = tb[1] / IMG, w = tb[2] / IMG, h = tb[3] / IMG;
        t_cx[tid] = cx; t_cy[tid] = cy; t_w[tid] = w; t_h[tid] = h;
        float x0 = cx - w * 0.5f, y0 = cy - h * 0.5f;
        float x1 = cx + w * 0.5f, y1 = cy + h * 0.5f;
        t_x0s[tid] = x0; t_y0s[tid] = y0; t_x1s[tid] = x1; t_y1s[tid] = y1;
        t_areas[tid] = (x1 - x0) * (y1 - y0);
        t_lab[tid] = tgt_labels[(size_t)b * NN + tid];
    }
    __syncthreads();

    float tx0[NN], ty0[NN], tx1[NN], ty1[NN], tar[NN];
#pragma unroll
    for (int n = 0; n < NN; ++n) {
        tx0[n] = t_x0s[n]; ty0[n] = t_y0s[n];
        tx1[n] = t_x1s[n]; ty1[n] = t_y1s[n];
        tar[n] = t_areas[n];
    }

    float bestv[NN];
    int   bestp[NN];
#pragma unroll
    for (int n = 0; n < NN; ++n) { bestv[n] = -1.0f; bestp[n] = 0x7fffffff; }

    for (int p = tid; p < PP; p += K1_THREADS) {
        float4 d = *reinterpret_cast<const float4*>(dboxes + (size_t)p * 4);
        float dx0 = d.x - d.z * 0.5f, dy0 = d.y - d.w * 0.5f;
        float dx1 = d.x + d.z * 0.5f, dy1 = d.y + d.w * 0.5f;
        float dar = (dx1 - dx0) * (dy1 - dy0);

        float iou[NN];
#pragma unroll
        for (int n = 0; n < NN; ++n) {
            float lx = fmaxf(tx0[n], dx0);
            float ly = fmaxf(ty0[n], dy0);
            float rx = fminf(tx1[n], dx1);
            float ry = fminf(ty1[n], dy1);
            float iw = fmaxf(rx - lx, 0.0f);
            float ih = fmaxf(ry - ly, 0.0f);
            float inter = iw * ih;
            float den   = tar[n] + dar - inter;          // > 0 always
            iou[n] = inter * __builtin_amdgcn_rcpf(den); // independent rcp per n
        }
        float bov = iou[0];
#pragma unroll
        for (int n = 1; n < NN; ++n) bov = fmaxf(bov, iou[n]);
        int bidx = 0;
#pragma unroll
        for (int n = NN - 1; n >= 0; --n) if (iou[n] == bov) bidx = n;
#pragma unroll
        for (int n = 0; n < NN; ++n) {
            if (iou[n] > bestv[n]) { bestv[n] = iou[n]; bestp[n] = p; }
        }
        obj_s[p] = (unsigned char)bidx;
        chk_s[p] = (bov > 0.5f) ? 1 : 0;
    }

#pragma unroll
    for (int n = 0; n < NN; ++n) {
        float v = bestv[n]; int ip = bestp[n];
        for (int off = 32; off; off >>= 1) {
            float v2 = __shfl_xor(v, off);
            int   p2 = __shfl_xor(ip, off);
            if (v2 > v || (v2 == v && p2 < ip)) { v = v2; ip = p2; }
        }
        if ((tid & 63) == 0) { red_v[n][tid >> 6] = v; red_i[n][tid >> 6] = ip; }
    }
    __syncthreads();
    if (tid < NN) {
        float v = red_v[tid][0]; int ip = red_i[tid][0];
        for (int w = 1; w < NW; ++w) {
            float v2 = red_v[tid][w]; int p2 = red_i[tid][w];
            if (v2 > v || (v2 == v && p2 < ip)) { v = v2; ip = p2; }
        }
        box_idx_s[tid] = ip;
    }
    __syncthreads();
    if (tid == 0) {
        for (int n = 0; n < NN; ++n) obj_s[box_idx_s[n]] = (unsigned char)n;
    }
    __syncthreads();

    float bacc = 0.0f;
    int   pcnt = 0;
    for (int p = tid; p < PP; p += K1_THREADS) {
        int lab = 0;
        if (chk_s[p]) {
            int n = obj_s[p];
            lab = t_lab[n];
            if (lab != 0) {
                ++pcnt;
                float4 d = *reinterpret_cast<const float4*>(dboxes + (size_t)p * 4);
                float gx = (t_cx[n] - d.x) / (d.z / 10.0f);
                float gy = (t_cy[n] - d.y) / (d.w / 10.0f);
                float gw = logf(t_w[n] / d.z) * 5.0f;
                float gh = logf(t_h[n] / d.w) * 5.0f;
                float4 pv = *reinterpret_cast<const float4*>(pred_boxes + ((size_t)b * PP + p) * 4);
                float dfs[4] = { pv.x - gx, pv.y - gy, pv.z - gw, pv.w - gh };
#pragma unroll
                for (int j = 0; j < 4; ++j) {
                    float ad = fabsf(dfs[j]);
                    bacc += (ad < 1.0f) ? 0.5f * ad * ad : ad - 0.5f;
                }
            }
        }
        tlab_out[(size_t)b * PP + p] = lab;
    }
    for (int off = 32; off; off >>= 1) {
        bacc += __shfl_xor(bacc, off);
        pcnt += __shfl_xor(pcnt, off);
    }
    if ((tid & 63) == 0) { red_f[tid >> 6] = bacc; red_c[tid >> 6] = pcnt; }
    __syncthreads();
    if (tid == 0) {
        float s = 0.0f; int c = 0;
        for (int w = 0; w < NW; ++w) { s += red_f[w]; c += red_c[w]; }
        bbox_partial[b] = s;
        pos_count[b]    = c;
    }
}

// ---------------------------------------------------------------------------
// Kernel 2 (v4): one 64-row tile per 256-thread block, 4 threads per row.
// (byte-identical to rounds 10-16)
// grid = NT x 256
// ---------------------------------------------------------------------------
__global__ __launch_bounds__(256) void k2_cls(
    const float* __restrict__ scores,  // [B*P, C]
    const int*   __restrict__ tlab,    // [B*P]
    float* __restrict__ neg,           // [B*P]
    float* __restrict__ clspos_partial)// [NT]
{
    __shared__ float slds[TILE_ROWS * CC];   // 64 x 81 floats = 20736 B
    const int tid = threadIdx.x;
    const int t   = blockIdx.x;

    const float* g = scores + (size_t)t * (TILE_ROWS * CC);
    for (int i = tid; i < TILE_ROWS * CC; i += 256)
        slds[i] = g[i];                      // coalesced, 256B/wave-instr
    __syncthreads();

    const int row = tid >> 2;                // 0..63
    const int q   = tid & 3;                 // quarter of the row
    const float* myrow = &slds[row * CC];
    const int base = q * 20;

    float x[21];
#pragma unroll
    for (int i = 0; i < 20; ++i) x[i] = myrow[base + i];
    x[20] = (q == 3) ? myrow[80] : -1e30f;

    float m = x[0];
#pragma unroll
    for (int i = 1; i < 21; ++i) m = fmaxf(m, x[i]);
    m = fmaxf(m, __shfl_xor(m, 1));
    m = fmaxf(m, __shfl_xor(m, 2));          // all 4 lanes hold row max M

    float s0 = 0.0f, s1 = 0.0f, s2 = 0.0f, s3 = 0.0f;
#pragma unroll
    for (int i = 0; i < 20; i += 4) {
        s0 += __expf(x[i + 0] - m);
        s1 += __expf(x[i + 1] - m);
        s2 += __expf(x[i + 2] - m);
        s3 += __expf(x[i + 3] - m);
    }
    s0 += __expf(x[20] - m);
    float s = (s0 + s1) + (s2 + s3);
    s += __shfl_xor(s, 1);
    s += __shfl_xor(s, 2);                   // all 4 lanes hold row sum S

    float acc = 0.0f;
    if (q == 0) {
        long long r = (long long)t * TILE_ROWS + row;
        int   lab = tlab[r];
        float cls = m + __logf(s) - slds[row * CC + lab];
        if (lab != 0) { acc = cls; neg[r] = 0.0f; }
        else          { neg[r] = cls; }
    }

    for (int off = 32; off; off >>= 1) acc += __shfl_xor(acc, off);
    __shared__ float wsum[4];
    if ((tid & 63) == 0) wsum[tid >> 6] = acc;
    __syncthreads();
    if (tid == 0)
        clspos_partial[t] = wsum[0] + wsum[1] + wsum[2] + wsum[3];
}

// ---------------------------------------------------------------------------
// Kernel 3 (v8): = v7 with two isolated micro-fixes:
//  (a) vals load as uint4 (9 wide iters vs 35 scalar; 16B-aligned per image)
//  (b) plain hist[256] (r5/r6 proved replica hist ~= plain: removes the
//      32-iter LDS zero + 32-iter sum passes per round)
// Wave-parallel scan, clspos pre-reduction, last-block finalize unchanged.
// grid = BB x 256
// ---------------------------------------------------------------------------
#define CH ((NT + BB - 1) / BB)   // 137 slice elements per block
__global__ __launch_bounds__(256) void k3_topk_final(
    const float* __restrict__ neg,
    const int*   __restrict__ pos_count,
    const float* __restrict__ clspos_partial,
    const float* __restrict__ bbox_partial,
    float* __restrict__ hard_partial,
    float* __restrict__ clspos_red,
    int*   __restrict__ done,
    float* __restrict__ out)
{
    const int b    = blockIdx.x;
    const int tid  = threadIdx.x;
    const int lane = tid & 63;
    const int wv   = tid >> 6;                // 0..3

    __shared__ unsigned int vals[PP];         // 34928 B
    __shared__ int hist[256];                 // 1 KB (plain; r6: replicas null)
    __shared__ int waveTot[4];
    __shared__ unsigned int s_prefix;
    __shared__ int s_kk;
    __shared__ float wsum[4];
    __shared__ float wsumc[4];
    __shared__ int s_last;

    // uint4 vals load: PP/4 = 2183 vecs; neg + b*PP is 16B-aligned (PP*4%16==0)
    {
        const uint4* src = reinterpret_cast<const uint4*>(neg + (size_t)b * PP);
        uint4* dst = reinterpret_cast<uint4*>(vals);
        for (int i = tid; i < PP / 4; i += 256) dst[i] = src[i];
    }

    // clspos slice pre-reduction (one coalesced load per thread)
    {
        int start = b * CH;
        int end   = start + CH; if (end > NT) end = NT;
        float cv = (start + tid < end) ? clspos_partial[start + tid] : 0.0f;
        for (int off = 32; off; off >>= 1) cv += __shfl_xor(cv, off);
        if (lane == 0) wsumc[wv] = cv;
    }

    int k = pos_count[b] * 3;
    if (k > PP) k = PP;
    if (tid == 0) { s_prefix = 0u; s_kk = k; }
    __syncthreads();                          // vals, wsumc, init visible
    if (tid == 0)
        clspos_red[b] = wsumc[0] + wsumc[1] + wsumc[2] + wsumc[3];

    float hp = 0.0f;
    if (k > 0) {
        unsigned int prefmask = 0u;
        for (int round = 0; round < 4; ++round) {
            const int shift = 24 - 8 * round;
            hist[tid] = 0;                    // 1 instr (vs 32-iter histR zero)
            __syncthreads();                  // A: zero done; prev s_* visible
            const unsigned int pref = s_prefix;
            const int kkR = s_kk;
            for (int i = tid; i < PP; i += 256) {
                unsigned int v = vals[i];
                if ((v & prefmask) == pref)
                    atomicAdd(&hist[(v >> shift) & 0xFF], 1);
            }
            __syncthreads();                  // B: histogram complete
            int myh = hist[tid];              // 1 read (vs 32-iter replica sum)
            int s = myh;                      // wave-local suffix-inclusive scan
#pragma unroll
            for (int off = 1; off < 64; off <<= 1) {
                int v = __shfl_down(s, off);
                if (lane + off < 64) s += v;
            }
            if (lane == 0) waveTot[wv] = s;
            __syncthreads();                  // C: waveTot published
            int addhi = 0;
            for (int w2 = wv + 1; w2 < 4; ++w2) addhi += waveTot[w2];
            s += addhi;                       // global suffix-inclusive over bins
            int sg = s - myh;                 // count strictly greater than bin tid
            if (sg < kkR && sg + myh >= kkR) {    // exactly one bin satisfies
                s_prefix = pref | ((unsigned int)tid << shift);
                s_kk     = kkR - sg;
            }
            prefmask |= (0xFFu << shift);
            // next round's barrier A separates this write from its readers
        }
        __syncthreads();                      // final selection visible

        unsigned int t = s_prefix;
        int kk = s_kk;
        float tf = __uint_as_float(t);

        float acc = 0.0f;
        for (int i = tid; i < PP; i += 256) {
            unsigned int v = vals[i];
            if (v > t) acc += __uint_as_float(v);
        }
        for (int off = 32; off; off >>= 1) acc += __shfl_xor(acc, off);
        if (lane == 0) wsum[wv] = acc;
        __syncthreads();
        if (tid == 0)
            hp = wsum[0] + wsum[1] + wsum[2] + wsum[3] + (float)kk * tf;
    }
    if (tid == 0) hard_partial[b] = hp;

    // ---- last-block finalize ----
    __threadfence();                          // release our global writes
    if (tid == 0) s_last = (atomicAdd(done, 1) == BB - 1) ? 1 : 0;
    __syncthreads();
    if (!s_last) return;
    __threadfence();                          // acquire other blocks' writes

    float cacc = 0.0f, bacc = 0.0f, hacc = 0.0f;
    int   pacc = 0;
    if (tid < BB) {
        cacc = clspos_red[tid];
        bacc = bbox_partial[tid];
        hacc = hard_partial[tid];
        pacc = pos_count[tid];
    }
    __shared__ float sc[256], sb[256], sh[256];
    __shared__ int   sp[256];
    sc[tid] = cacc; sb[tid] = bacc; sh[tid] = hacc; sp[tid] = pacc;
    __syncthreads();
    for (int off = 128; off; off >>= 1) {
        if (tid < off) {
            sc[tid] += sc[tid + off];
            sb[tid] += sb[tid + off];
            sh[tid] += sh[tid + off];
            sp[tid] += sp[tid + off];
        }
        __syncthreads();
    }
    if (tid == 0) {
        float npos = fmaxf((float)sp[0], 1.0f);
        out[0] = (sc[0] + sh[0]) / npos + sb[0] / (npos * 4.0f);
    }
}

// ---------------------------------------------------------------------------
extern "C" void kernel_launch(void* const* d_in, const int* in_sizes, int n_in,
                              void* d_out, int out_size, void* d_ws, size_t ws_size,
                              hipStream_t stream) {
    const float* pred_boxes  = (const float*)d_in[0];
    const float* pred_scores = (const float*)d_in[1];
    const float* tgt_boxes   = (const float*)d_in[2];
    const int*   tgt_labels  = (const int*)d_in[3];
    const float* dboxes      = (const float*)d_in[4];
    float* out = (float*)d_out;

    char* ws = (char*)d_ws;
    int*   tlab           = (int*)ws;   ws += (size_t)BB * PP * sizeof(int);
    float* neg            = (float*)ws; ws += (size_t)BB * PP * sizeof(float);
    int*   pos_count      = (int*)ws;   ws += BB * sizeof(int);
    float* bbox_partial   = (float*)ws; ws += BB * sizeof(float);
    float* hard_partial   = (float*)ws; ws += BB * sizeof(float);
    float* clspos_red     = (float*)ws; ws += BB * sizeof(float);
    int*   k3_done        = (int*)ws;   ws += 4 * sizeof(int);
    float* clspos_partial = (float*)ws; ws += (size_t)NT * sizeof(float);

    k1_match<<<BB, K1_THREADS, 0, stream>>>(pred_boxes, tgt_boxes, tgt_labels, dboxes,
                                            tlab, bbox_partial, pos_count, k3_done);
    k2_cls<<<NT, 256, 0, stream>>>(pred_scores, tlab, neg, clspos_partial);
    k3_topk_final<<<BB, 256, 0, stream>>>(neg, pos_count, clspos_partial,
                                          bbox_partial, hard_partial, clspos_red,
                                          k3_done, out);
}

// Round 21
// 139.751 us; speedup vs baseline: 1.4124x; 1.0425x over previous
//
#include <hip/hip_runtime.h>
#include <hip/hip_bf16.h>
#include <math.h>

#define BB 128
#define PP 8732
#define NN 16
#define CC 81
#define IMG 300.0f
#define TILE_ROWS 64
#define NT ((BB * PP) / TILE_ROWS)   // 17464 tiles, exact
#define K1_THREADS 512

// ---------------------------------------------------------------------------
// Kernel 1 (v4b): ILP-restructured matching. (byte-identical to round 16's
// 140.1us best config)
// grid = BB blocks, 512 threads
// ---------------------------------------------------------------------------
__global__ __launch_bounds__(K1_THREADS) void k1_match(
    const float* __restrict__ pred_boxes,   // [B,P,4]
    const float* __restrict__ tgt_boxes,    // [B,N,4] pixel cxcywh
    const int*   __restrict__ tgt_labels,   // [B,N]
    const float* __restrict__ dboxes,       // [P,4] cxcywh (clipped)
    int*   __restrict__ tlab_out,           // [B,P]
    float* __restrict__ bbox_partial,       // [B]
    int*   __restrict__ pos_count,          // [B]
    int*   __restrict__ k3_done)            // [1] completion counter
{
    const int b   = blockIdx.x;
    const int tid = threadIdx.x;
    const int NW  = K1_THREADS / 64;

    if (b == 0 && tid == 0) *k3_done = 0;   // replay-safe reset (runs before k3)

    __shared__ float t_cx[NN], t_cy[NN], t_w[NN], t_h[NN];
    __shared__ float t_x0s[NN], t_y0s[NN], t_x1s[NN], t_y1s[NN], t_areas[NN];
    __shared__ int   t_lab[NN];
    __shared__ unsigned char obj_s[PP];
    __shared__ unsigned char chk_s[PP];
    __shared__ float red_v[NN][NW];
    __shared__ int   red_i[NN][NW];
    __shared__ int   box_idx_s[NN];
    __shared__ float red_f[NW];
    __shared__ int   red_c[NW];

    if (tid < NN) {
        const float* tb = tgt_boxes + ((size_t)b * NN + tid) * 4;
        float cx = tb[0] / IMG, cy = tb[1] / IMG, w = tb[2] / IMG, h = tb[3] / IMG;
        t_cx[tid] = cx; t_cy[tid] = cy; t_w[tid] = w; t_h[tid] = h;
        float x0 = cx - w * 0.5f, y0 = cy - h * 0.5f;
        float x1 = cx + w * 0.5f, y1 = cy + h * 0.5f;
        t_x0s[tid] = x0; t_y0s[tid] = y0; t_x1s[tid] = x1; t_y1s[tid] = y1;
        t_areas[tid] = (x1 - x0) * (y1 - y0);
        t_lab[tid] = tgt_labels[(size_t)b * NN + tid];
    }
    __syncthreads();

    float tx0[NN], ty0[NN], tx1[NN], ty1[NN], tar[NN];
#pragma unroll
    for (int n = 0; n < NN; ++n) {
        tx0[n] = t_x0s[n]; ty0[n] = t_y0s[n];
        tx1[n] = t_x1s[n]; ty1[n] = t_y1s[n];
        tar[n] = t_areas[n];
    }

    float bestv[NN];
    int   bestp[NN];
#pragma unroll
    for (int n = 0; n < NN; ++n) { bestv[n] = -1.0f; bestp[n] = 0x7fffffff; }

    for (int p = tid; p < PP; p += K1_THREADS) {
        float4 d = *reinterpret_cast<const float4*>(dboxes + (size_t)p * 4);
        float dx0 = d.x - d.z * 0.5f, dy0 = d.y - d.w * 0.5f;
        float dx1 = d.x + d.z * 0.5f, dy1 = d.y + d.w * 0.5f;
        float dar = (dx1 - dx0) * (dy1 - dy0);

        float iou[NN];
#pragma unroll
        for (int n = 0; n < NN; ++n) {
            float lx = fmaxf(tx0[n], dx0);
            float ly = fmaxf(ty0[n], dy0);
            float rx = fminf(tx1[n], dx1);
            float ry = fminf(ty1[n], dy1);
            float iw = fmaxf(rx - lx, 0.0f);
            float ih = fmaxf(ry - ly, 0.0f);
            float inter = iw * ih;
            float den   = tar[n] + dar - inter;          // > 0 always
            iou[n] = inter * __builtin_amdgcn_rcpf(den); // independent rcp per n
        }
        float bov = iou[0];
#pragma unroll
        for (int n = 1; n < NN; ++n) bov = fmaxf(bov, iou[n]);
        int bidx = 0;
#pragma unroll
        for (int n = NN - 1; n >= 0; --n) if (iou[n] == bov) bidx = n;
#pragma unroll
        for (int n = 0; n < NN; ++n) {
            if (iou[n] > bestv[n]) { bestv[n] = iou[n]; bestp[n] = p; }
        }
        obj_s[p] = (unsigned char)bidx;
        chk_s[p] = (bov > 0.5f) ? 1 : 0;
    }

#pragma unroll
    for (int n = 0; n < NN; ++n) {
        float v = bestv[n]; int ip = bestp[n];
        for (int off = 32; off; off >>= 1) {
            float v2 = __shfl_xor(v, off);
            int   p2 = __shfl_xor(ip, off);
            if (v2 > v || (v2 == v && p2 < ip)) { v = v2; ip = p2; }
        }
        if ((tid & 63) == 0) { red_v[n][tid >> 6] = v; red_i[n][tid >> 6] = ip; }
    }
    __syncthreads();
    if (tid < NN) {
        float v = red_v[tid][0]; int ip = red_i[tid][0];
        for (int w = 1; w < NW; ++w) {
            float v2 = red_v[tid][w]; int p2 = red_i[tid][w];
            if (v2 > v || (v2 == v && p2 < ip)) { v = v2; ip = p2; }
        }
        box_idx_s[tid] = ip;
    }
    __syncthreads();
    if (tid == 0) {
        for (int n = 0; n < NN; ++n) obj_s[box_idx_s[n]] = (unsigned char)n;
    }
    __syncthreads();

    float bacc = 0.0f;
    int   pcnt = 0;
    for (int p = tid; p < PP; p += K1_THREADS) {
        int lab = 0;
        if (chk_s[p]) {
            int n = obj_s[p];
            lab = t_lab[n];
            if (lab != 0) {
                ++pcnt;
                float4 d = *reinterpret_cast<const float4*>(dboxes + (size_t)p * 4);
                float gx = (t_cx[n] - d.x) / (d.z / 10.0f);
                float gy = (t_cy[n] - d.y) / (d.w / 10.0f);
                float gw = logf(t_w[n] / d.z) * 5.0f;
                float gh = logf(t_h[n] / d.w) * 5.0f;
                float4 pv = *reinterpret_cast<const float4*>(pred_boxes + ((size_t)b * PP + p) * 4);
                float dfs[4] = { pv.x - gx, pv.y - gy, pv.z - gw, pv.w - gh };
#pragma unroll
                for (int j = 0; j < 4; ++j) {
                    float ad = fabsf(dfs[j]);
                    bacc += (ad < 1.0f) ? 0.5f * ad * ad : ad - 0.5f;
                }
            }
        }
        tlab_out[(size_t)b * PP + p] = lab;
    }
    for (int off = 32; off; off >>= 1) {
        bacc += __shfl_xor(bacc, off);
        pcnt += __shfl_xor(pcnt, off);
    }
    if ((tid & 63) == 0) { red_f[tid >> 6] = bacc; red_c[tid >> 6] = pcnt; }
    __syncthreads();
    if (tid == 0) {
        float s = 0.0f; int c = 0;
        for (int w = 0; w < NW; ++w) { s += red_f[w]; c += red_c[w]; }
        bbox_partial[b] = s;
        pos_count[b]    = c;
    }
}

// ---------------------------------------------------------------------------
// Kernel 2 (v4): one 64-row tile per 256-thread block, 4 threads per row.
// (byte-identical to rounds 10-16)
// grid = NT x 256
// ---------------------------------------------------------------------------
__global__ __launch_bounds__(256) void k2_cls(
    const float* __restrict__ scores,  // [B*P, C]
    const int*   __restrict__ tlab,    // [B*P]
    float* __restrict__ neg,           // [B*P]
    float* __restrict__ clspos_partial)// [NT]
{
    __shared__ float slds[TILE_ROWS * CC];   // 64 x 81 floats = 20736 B
    const int tid = threadIdx.x;
    const int t   = blockIdx.x;

    const float* g = scores + (size_t)t * (TILE_ROWS * CC);
    for (int i = tid; i < TILE_ROWS * CC; i += 256)
        slds[i] = g[i];                      // coalesced, 256B/wave-instr
    __syncthreads();

    const int row = tid >> 2;                // 0..63
    const int q   = tid & 3;                 // quarter of the row
    const float* myrow = &slds[row * CC];
    const int base = q * 20;

    float x[21];
#pragma unroll
    for (int i = 0; i < 20; ++i) x[i] = myrow[base + i];
    x[20] = (q == 3) ? myrow[80] : -1e30f;

    float m = x[0];
#pragma unroll
    for (int i = 1; i < 21; ++i) m = fmaxf(m, x[i]);
    m = fmaxf(m, __shfl_xor(m, 1));
    m = fmaxf(m, __shfl_xor(m, 2));          // all 4 lanes hold row max M

    float s0 = 0.0f, s1 = 0.0f, s2 = 0.0f, s3 = 0.0f;
#pragma unroll
    for (int i = 0; i < 20; i += 4) {
        s0 += __expf(x[i + 0] - m);
        s1 += __expf(x[i + 1] - m);
        s2 += __expf(x[i + 2] - m);
        s3 += __expf(x[i + 3] - m);
    }
    s0 += __expf(x[20] - m);
    float s = (s0 + s1) + (s2 + s3);
    s += __shfl_xor(s, 1);
    s += __shfl_xor(s, 2);                   // all 4 lanes hold row sum S

    float acc = 0.0f;
    if (q == 0) {
        long long r = (long long)t * TILE_ROWS + row;
        int   lab = tlab[r];
        float cls = m + __logf(s) - slds[row * CC + lab];
        if (lab != 0) { acc = cls; neg[r] = 0.0f; }
        else          { neg[r] = cls; }
    }

    for (int off = 32; off; off >>= 1) acc += __shfl_xor(acc, off);
    __shared__ float wsum[4];
    if ((tid & 63) == 0) wsum[tid >> 6] = acc;
    __syncthreads();
    if (tid == 0)
        clspos_partial[t] = wsum[0] + wsum[1] + wsum[2] + wsum[3];
}

// ---------------------------------------------------------------------------
// Kernel 3 (v7): radix-select, wave-parallel scan, replica hist, last-block
// finalize. (byte-identical to rounds 14-16)
// grid = BB x 256
// ---------------------------------------------------------------------------
#define HREP 32
#define HPAD 257
#define CH   ((NT + BB - 1) / BB)   // 137 slice elements per block
__global__ __launch_bounds__(256) void k3_topk_final(
    const float* __restrict__ neg,
    const int*   __restrict__ pos_count,
    const float* __restrict__ clspos_partial,
    const float* __restrict__ bbox_partial,
    float* __restrict__ hard_partial,
    float* __restrict__ clspos_red,
    int*   __restrict__ done,
    float* __restrict__ out)
{
    const int b    = blockIdx.x;
    const int tid  = threadIdx.x;
    const int lane = tid & 63;
    const int wv   = tid >> 6;                // 0..3
    const int rep  = lane >> 1;               // 32 replicas, 2 lanes each

    __shared__ unsigned int vals[PP];         // 34928 B
    __shared__ int histR[HREP * HPAD];        // 32896 B
    __shared__ int waveTot[4];
    __shared__ unsigned int s_prefix;
    __shared__ int s_kk;
    __shared__ float wsum[4];
    __shared__ float wsumc[4];
    __shared__ int s_last;

    for (int i = tid; i < PP; i += 256)
        vals[i] = __float_as_uint(neg[(size_t)b * PP + i]);

    {
        int start = b * CH;
        int end   = start + CH; if (end > NT) end = NT;
        float cv = (start + tid < end) ? clspos_partial[start + tid] : 0.0f;
        for (int off = 32; off; off >>= 1) cv += __shfl_xor(cv, off);
        if (lane == 0) wsumc[wv] = cv;
    }

    int k = pos_count[b] * 3;
    if (k > PP) k = PP;
    if (tid == 0) { s_prefix = 0u; s_kk = k; }
    __syncthreads();
    if (tid == 0)
        clspos_red[b] = wsumc[0] + wsumc[1] + wsumc[2] + wsumc[3];

    float hp = 0.0f;
    if (k > 0) {
        unsigned int prefmask = 0u;
        for (int round = 0; round < 4; ++round) {
            const int shift = 24 - 8 * round;
            for (int i = tid; i < HREP * HPAD; i += 256) histR[i] = 0;
            __syncthreads();
            const unsigned int pref = s_prefix;
            const int kkR = s_kk;
            for (int i = tid; i < PP; i += 256) {
                unsigned int v = vals[i];
                if ((v & prefmask) == pref)
                    atomicAdd(&histR[rep * HPAD + ((v >> shift) & 0xFF)], 1);
            }
            __syncthreads();
            int myh = 0;
#pragma unroll 8
            for (int r = 0; r < HREP; ++r) myh += histR[r * HPAD + tid];
            int s = myh;
#pragma unroll
            for (int off = 1; off < 64; off <<= 1) {
                int v = __shfl_down(s, off);
                if (lane + off < 64) s += v;
            }
            if (lane == 0) waveTot[wv] = s;
            __syncthreads();
            int addhi = 0;
            for (int w2 = wv + 1; w2 < 4; ++w2) addhi += waveTot[w2];
            s += addhi;
            int sg = s - myh;
            if (sg < kkR && sg + myh >= kkR) {
                s_prefix = pref | ((unsigned int)tid << shift);
                s_kk     = kkR - sg;
            }
            prefmask |= (0xFFu << shift);
        }
        __syncthreads();

        unsigned int t = s_prefix;
        int kk = s_kk;
        float tf = __uint_as_float(t);

        float acc = 0.0f;
        for (int i = tid; i < PP; i += 256) {
            unsigned int v = vals[i];
            if (v > t) acc += __uint_as_float(v);
        }
        for (int off = 32; off; off >>= 1) acc += __shfl_xor(acc, off);
        if (lane == 0) wsum[wv] = acc;
        __syncthreads();
        if (tid == 0)
            hp = wsum[0] + wsum[1] + wsum[2] + wsum[3] + (float)kk * tf;
    }
    if (tid == 0) hard_partial[b] = hp;

    __threadfence();
    if (tid == 0) s_last = (atomicAdd(done, 1) == BB - 1) ? 1 : 0;
    __syncthreads();
    if (!s_last) return;
    __threadfence();

    float cacc = 0.0f, bacc = 0.0f, hacc = 0.0f;
    int   pacc = 0;
    if (tid < BB) {
        cacc = clspos_red[tid];
        bacc = bbox_partial[tid];
        hacc = hard_partial[tid];
        pacc = pos_count[tid];
    }
    __shared__ float sc[256], sb[256], sh[256];
    __shared__ int   sp[256];
    sc[tid] = cacc; sb[tid] = bacc; sh[tid] = hacc; sp[tid] = pacc;
    __syncthreads();
    for (int off = 128; off; off >>= 1) {
        if (tid < off) {
            sc[tid] += sc[tid + off];
            sb[tid] += sb[tid + off];
            sh[tid] += sh[tid + off];
            sp[tid] += sp[tid + off];
        }
        __syncthreads();
    }
    if (tid == 0) {
        float npos = fmaxf((float)sp[0], 1.0f);
        out[0] = (sc[0] + sh[0]) / npos + sb[0] / (npos * 4.0f);
    }
}

// ---------------------------------------------------------------------------
extern "C" void kernel_launch(void* const* d_in, const int* in_sizes, int n_in,
                              void* d_out, int out_size, void* d_ws, size_t ws_size,
                              hipStream_t stream) {
    const float* pred_boxes  = (const float*)d_in[0];
    const float* pred_scores = (const float*)d_in[1];
    const float* tgt_boxes   = (const float*)d_in[2];
    const int*   tgt_labels  = (const int*)d_in[3];
    const float* dboxes      = (const float*)d_in[4];
    float* out = (float*)d_out;

    char* ws = (char*)d_ws;
    int*   tlab           = (int*)ws;   ws += (size_t)BB * PP * sizeof(int);
    float* neg            = (float*)ws; ws += (size_t)BB * PP * sizeof(float);
    int*   pos_count      = (int*)ws;   ws += BB * sizeof(int);
    float* bbox_partial   = (float*)ws; ws += BB * sizeof(float);
    float* hard_partial   = (float*)ws; ws += BB * sizeof(float);
    float* clspos_red     = (float*)ws; ws += BB * sizeof(float);
    int*   k3_done        = (int*)ws;   ws += 4 * sizeof(int);
    float* clspos_partial = (float*)ws; ws += (size_t)NT * sizeof(float);

    k1_match<<<BB, K1_THREADS, 0, stream>>>(pred_boxes, tgt_boxes, tgt_labels, dboxes,
                                            tlab, bbox_partial, pos_count, k3_done);
    k2_cls<<<NT, 256, 0, stream>>>(pred_scores, tlab, neg, clspos_partial);
    k3_topk_final<<<BB, 256, 0, stream>>>(neg, pos_count, clspos_partial,
                                          bbox_partial, hard_partial, clspos_red,
                                          k3_done, out);
}